// Round 1
// baseline (326.196 us; speedup 1.0000x reference)
//
#include <hip/hip_runtime.h>

// FeatureCorrelation: B=8192 rows x 3 steps x D=2048 fp32.
// Per row: 9 scalar reductions -> 12 weights -> 3 linear-combo outputs.
// Memory-bound: 201 MB in + 201 MB out; target ~67 us @ ~6 TB/s.

constexpr int D   = 2048;
constexpr int TPB = 256;                 // 4 waves; D/TPB = 8 floats = 2 float4 per vector per thread
constexpr float EPS_PD = 1e-6f;
constexpr float EPS_CS = 1e-8f;

__global__ __launch_bounds__(TPB) void feat_corr_kernel(
    const float* __restrict__ feat,
    const float* __restrict__ pos,
    float* __restrict__ out)
{
    const int b   = blockIdx.x;
    const int tid = threadIdx.x;

    const size_t row = (size_t)b * (3 * D);
    const float4* r1 = (const float4*)(feat + row);
    const float4* r2 = (const float4*)(feat + row + D);
    const float4* r3 = (const float4*)(feat + row + 2 * D);
    const float4* p1 = (const float4*)(pos);
    const float4* p2 = (const float4*)(pos + D);
    const float4* p3 = (const float4*)(pos + 2 * D);

    // Load + add positional embedding; keep everything in registers.
    float4 x1[2], x2[2], x3[2];
#pragma unroll
    for (int j = 0; j < 2; ++j) {
        const int idx = tid + j * TPB;   // coalesced: consecutive lanes -> consecutive float4
        float4 a = r1[idx], pa = p1[idx];
        float4 v = r2[idx], pb = p2[idx];
        float4 c = r3[idx], pc = p3[idx];
        x1[j] = make_float4(a.x + pa.x, a.y + pa.y, a.z + pa.z, a.w + pa.w);
        x2[j] = make_float4(v.x + pb.x, v.y + pb.y, v.z + pb.z, v.w + pb.w);
        x3[j] = make_float4(c.x + pc.x, c.y + pc.y, c.z + pc.z, c.w + pc.w);
    }

    // 9 per-thread partial sums.
    float n1s = 0.f, n2s = 0.f, n3s = 0.f;
    float d12 = 0.f, d13 = 0.f, d23 = 0.f;
    float s1  = 0.f, s2  = 0.f, s3  = 0.f;
#pragma unroll
    for (int j = 0; j < 2; ++j) {
        const float* a = (const float*)&x1[j];
        const float* v = (const float*)&x2[j];
        const float* c = (const float*)&x3[j];
#pragma unroll
        for (int k = 0; k < 4; ++k) {
            const float u = a[k], w = v[k], z = c[k];
            n1s = fmaf(u, u, n1s);
            n2s = fmaf(w, w, n2s);
            n3s = fmaf(z, z, n3s);
            d12 = fmaf(u, w, d12);
            d13 = fmaf(u, z, d13);
            d23 = fmaf(w, z, d23);
            s1 += u; s2 += w; s3 += z;
        }
    }

    // Wave (64-lane) shuffle reduction, then cross-wave via LDS.
    float vals[9] = {n1s, n2s, n3s, d12, d13, d23, s1, s2, s3};
#pragma unroll
    for (int off = 32; off > 0; off >>= 1) {
#pragma unroll
        for (int k = 0; k < 9; ++k)
            vals[k] += __shfl_down(vals[k], off, 64);
    }

    __shared__ float red[TPB / 64][9];
    const int wave = tid >> 6;
    const int lane = tid & 63;
    if (lane == 0) {
#pragma unroll
        for (int k = 0; k < 9; ++k) red[wave][k] = vals[k];
    }
    __syncthreads();

    float t[9];
#pragma unroll
    for (int k = 0; k < 9; ++k)
        t[k] = red[0][k] + red[1][k] + red[2][k] + red[3][k];   // broadcast reads, conflict-free

    const float N1s = t[0], N2s = t[1], N3s = t[2];
    const float D12 = t[3], D13 = t[4], D23 = t[5];
    const float S1  = t[6], S2  = t[7], S3  = t[8];

    // Weights (computed redundantly per thread -- cheap scalar math).
    const float n1 = fmaxf(sqrtf(N1s), EPS_CS);
    const float n2 = fmaxf(sqrtf(N2s), EPS_CS);
    const float n3 = fmaxf(sqrtf(N3s), EPS_CS);

    const float c12 = 0.5f + 0.5f * (D12 / (n1 * n2));  // cosine terms (symmetric)
    const float c13 = 0.5f + 0.5f * (D13 / (n1 * n3));
    const float c23 = 0.5f + 0.5f * (D23 / (n2 * n3));

    const float sq12 = N1s + N2s - 2.f * D12;           // sum((f1-f2)^2)
    const float sq13 = N1s + N3s - 2.f * D13;
    const float sq23 = N2s + N3s - 2.f * D23;
    const float De2  = (float)D * EPS_PD * EPS_PD;

    // 1/(1+sqrt(sum((fi-fj+eps)^2))), eps inside the square -> sign-dependent
    auto wdist = [&](float sqd, float ssum) {
        return 1.0f / (1.0f + sqrtf(sqd + 2.f * EPS_PD * ssum + De2));
    };
    const float w12 = wdist(sq12, S1 - S2);  // (f1-f2+e)
    const float w21 = wdist(sq12, S2 - S1);  // (f2-f1+e)
    const float w13 = wdist(sq13, S1 - S3);
    const float w31 = wdist(sq13, S3 - S1);
    const float w23 = wdist(sq23, S2 - S3);
    const float w32 = wdist(sq23, S3 - S2);

    // o1 = f1 + (w12+c12) f2 + (w13+c13) f3
    // o2 = f2 + (w21+c12) f1 + (w23+c23) f3
    // o3 = f3 + (w31+c13) f1 + (w32+c23) f2
    const float g1b = w12 + c12, g1c = w13 + c13;
    const float g2a = w21 + c12, g2c = w23 + c23;
    const float g3a = w31 + c13, g3b = w32 + c23;

    float4* o1 = (float4*)(out + row);
    float4* o2 = (float4*)(out + row + D);
    float4* o3 = (float4*)(out + row + 2 * D);
#pragma unroll
    for (int j = 0; j < 2; ++j) {
        const int idx = tid + j * TPB;
        const float* a = (const float*)&x1[j];
        const float* v = (const float*)&x2[j];
        const float* c = (const float*)&x3[j];
        float4 q1, q2, q3;
        float* q1p = (float*)&q1; float* q2p = (float*)&q2; float* q3p = (float*)&q3;
#pragma unroll
        for (int k = 0; k < 4; ++k) {
            q1p[k] = a[k] + g1b * v[k] + g1c * c[k];
            q2p[k] = v[k] + g2a * a[k] + g2c * c[k];
            q3p[k] = c[k] + g3a * a[k] + g3b * v[k];
        }
        o1[idx] = q1;
        o2[idx] = q2;
        o3[idx] = q3;
    }
}

extern "C" void kernel_launch(void* const* d_in, const int* in_sizes, int n_in,
                              void* d_out, int out_size, void* d_ws, size_t ws_size,
                              hipStream_t stream) {
    const float* feat = (const float*)d_in[0];
    const float* pos  = (const float*)d_in[1];
    float* out        = (float*)d_out;
    const int B = in_sizes[0] / (3 * D);   // 8192
    feat_corr_kernel<<<B, TPB, 0, stream>>>(feat, pos, out);
}

// Round 3
// 320.037 us; speedup vs baseline: 1.0192x; 1.0192x over previous
//
#include <hip/hip_runtime.h>

// FeatureCorrelation: B=8192 rows x 3 steps x D=2048 fp32.
// Per row: 9 scalar reductions -> 12 weights -> 3 linear-combo outputs.
// Pure streaming: 201 MB in (once) + 201 MB out (once); floor ~67 us @ 6.3 TB/s.
// R3: nontemporal via native ext_vector_type (HIP_vector_type rejected by builtin).

constexpr int D   = 2048;
constexpr int TPB = 256;                 // 4 waves; D/TPB = 8 floats = 2 vec4 per vector per thread
constexpr float EPS_PD = 1e-6f;
constexpr float EPS_CS = 1e-8f;

using fvec4 = __attribute__((ext_vector_type(4))) float;   // native vector: NT builtin-compatible

__global__ __launch_bounds__(TPB) void feat_corr_kernel(
    const float* __restrict__ feat,
    const float* __restrict__ pos,
    float* __restrict__ out)
{
    const int b   = blockIdx.x;
    const int tid = threadIdx.x;

    const size_t row = (size_t)b * (3 * D);
    const fvec4* r1 = (const fvec4*)(feat + row);
    const fvec4* r2 = (const fvec4*)(feat + row + D);
    const fvec4* r3 = (const fvec4*)(feat + row + 2 * D);
    const fvec4* p1 = (const fvec4*)(pos);
    const fvec4* p2 = (const fvec4*)(pos + D);
    const fvec4* p3 = (const fvec4*)(pos + 2 * D);

    const int i0 = tid;            // coalesced: consecutive lanes -> consecutive 16B
    const int i1 = tid + TPB;

    // Streamed feat loads first (HBM-latency critical), nontemporal (no L2 alloc).
    fvec4 a0 = __builtin_nontemporal_load(r1 + i0);
    fvec4 a1 = __builtin_nontemporal_load(r1 + i1);
    fvec4 b0 = __builtin_nontemporal_load(r2 + i0);
    fvec4 b1 = __builtin_nontemporal_load(r2 + i1);
    fvec4 c0 = __builtin_nontemporal_load(r3 + i0);
    fvec4 c1 = __builtin_nontemporal_load(r3 + i1);
    // pos: tiny, reused by all 8192 blocks -> normal cached loads.
    fvec4 pa0 = p1[i0], pa1 = p1[i1];
    fvec4 pb0 = p2[i0], pb1 = p2[i1];
    fvec4 pc0 = p3[i0], pc1 = p3[i1];

    fvec4 x1[2], x2[2], x3[2];
    x1[0] = a0 + pa0;  x1[1] = a1 + pa1;
    x2[0] = b0 + pb0;  x2[1] = b1 + pb1;
    x3[0] = c0 + pc0;  x3[1] = c1 + pc1;

    // 9 per-thread partial sums.
    float n1s = 0.f, n2s = 0.f, n3s = 0.f;
    float d12 = 0.f, d13 = 0.f, d23 = 0.f;
    float s1  = 0.f, s2  = 0.f, s3  = 0.f;
#pragma unroll
    for (int j = 0; j < 2; ++j) {
#pragma unroll
        for (int k = 0; k < 4; ++k) {
            const float u = x1[j][k], w = x2[j][k], z = x3[j][k];
            n1s = fmaf(u, u, n1s);
            n2s = fmaf(w, w, n2s);
            n3s = fmaf(z, z, n3s);
            d12 = fmaf(u, w, d12);
            d13 = fmaf(u, z, d13);
            d23 = fmaf(w, z, d23);
            s1 += u; s2 += w; s3 += z;
        }
    }

    // Wave (64-lane) shuffle reduction, then cross-wave via LDS.
    float vals[9] = {n1s, n2s, n3s, d12, d13, d23, s1, s2, s3};
#pragma unroll
    for (int off = 32; off > 0; off >>= 1) {
#pragma unroll
        for (int k = 0; k < 9; ++k)
            vals[k] += __shfl_down(vals[k], off, 64);
    }

    __shared__ float red[TPB / 64][9];
    const int wave = tid >> 6;
    const int lane = tid & 63;
    if (lane == 0) {
#pragma unroll
        for (int k = 0; k < 9; ++k) red[wave][k] = vals[k];
    }
    __syncthreads();

    float t[9];
#pragma unroll
    for (int k = 0; k < 9; ++k)
        t[k] = red[0][k] + red[1][k] + red[2][k] + red[3][k];   // broadcast reads, conflict-free

    const float N1s = t[0], N2s = t[1], N3s = t[2];
    const float D12 = t[3], D13 = t[4], D23 = t[5];
    const float S1  = t[6], S2  = t[7], S3  = t[8];

    // Weights (computed redundantly per thread -- cheap scalar math).
    const float n1 = fmaxf(sqrtf(N1s), EPS_CS);
    const float n2 = fmaxf(sqrtf(N2s), EPS_CS);
    const float n3 = fmaxf(sqrtf(N3s), EPS_CS);

    const float c12 = 0.5f + 0.5f * (D12 / (n1 * n2));  // cosine terms (symmetric)
    const float c13 = 0.5f + 0.5f * (D13 / (n1 * n3));
    const float c23 = 0.5f + 0.5f * (D23 / (n2 * n3));

    const float sq12 = N1s + N2s - 2.f * D12;           // sum((f1-f2)^2)
    const float sq13 = N1s + N3s - 2.f * D13;
    const float sq23 = N2s + N3s - 2.f * D23;
    const float De2  = (float)D * EPS_PD * EPS_PD;

    // 1/(1+sqrt(sum((fi-fj+eps)^2))), eps inside the square -> sign-dependent
    auto wdist = [&](float sqd, float ssum) {
        return 1.0f / (1.0f + sqrtf(sqd + 2.f * EPS_PD * ssum + De2));
    };
    const float w12 = wdist(sq12, S1 - S2);  // (f1-f2+e)
    const float w21 = wdist(sq12, S2 - S1);  // (f2-f1+e)
    const float w13 = wdist(sq13, S1 - S3);
    const float w31 = wdist(sq13, S3 - S1);
    const float w23 = wdist(sq23, S2 - S3);
    const float w32 = wdist(sq23, S3 - S2);

    // o1 = f1 + (w12+c12) f2 + (w13+c13) f3
    // o2 = f2 + (w21+c12) f1 + (w23+c23) f3
    // o3 = f3 + (w31+c13) f1 + (w32+c23) f2
    const float g1b = w12 + c12, g1c = w13 + c13;
    const float g2a = w21 + c12, g2c = w23 + c23;
    const float g3a = w31 + c13, g3b = w32 + c23;

    fvec4* o1 = (fvec4*)(out + row);
    fvec4* o2 = (fvec4*)(out + row + D);
    fvec4* o3 = (fvec4*)(out + row + 2 * D);
#pragma unroll
    for (int j = 0; j < 2; ++j) {
        const int idx = (j == 0) ? i0 : i1;
        fvec4 q1 = x1[j] + g1b * x2[j] + g1c * x3[j];
        fvec4 q2 = x2[j] + g2a * x1[j] + g2c * x3[j];
        fvec4 q3 = x3[j] + g3a * x1[j] + g3b * x2[j];
        __builtin_nontemporal_store(q1, o1 + idx);   // streamed out: no L2 write-allocate
        __builtin_nontemporal_store(q2, o2 + idx);
        __builtin_nontemporal_store(q3, o3 + idx);
    }
}

extern "C" void kernel_launch(void* const* d_in, const int* in_sizes, int n_in,
                              void* d_out, int out_size, void* d_ws, size_t ws_size,
                              hipStream_t stream) {
    const float* feat = (const float*)d_in[0];
    const float* pos  = (const float*)d_in[1];
    float* out        = (float*)d_out;
    const int B = in_sizes[0] / (3 * D);   // 8192
    feat_corr_kernel<<<B, TPB, 0, stream>>>(feat, pos, out);
}